// Round 8
// baseline (234.077 us; speedup 1.0000x reference)
//
#include <hip/hip_runtime.h>
#include <math.h>

#define B 32
#define K 4
#define C 256
#define HW 1024          // H*W = 32*32
#define NT 5             // K+1 tensors (y, x0..x3)
#define MID 32
#define FEAT 1280        // NT*C
#define EPS 1e-5f

#define OUT_F4   (B * C * HW / 4)   // 2,097,152 float4 in output
#define K3_BLKS  2048
#define K3_THR   256
#define K3_TOT   (K3_BLKS * K3_THR) // 524,288 threads -> 4 iters/thread

// ---------------------------------------------------------------------------
// Kernel 1 (round-2 exact): spatial mean per (tensor, b, c).  One wave per
// slice of HW=1024 floats, 4 coalesced float4 loads/lane, butterfly reduce.
// feats layout: [B][FEAT] slot t*C+c (t=0 is y, t=1..4 are x0..x3).
// ---------------------------------------------------------------------------
__global__ __launch_bounds__(256) void mean_kernel(
    const float* __restrict__ y,
    const float* __restrict__ x0, const float* __restrict__ x1,
    const float* __restrict__ x2, const float* __restrict__ x3,
    float* __restrict__ feats)
{
    int wave = (blockIdx.x << 2) + (threadIdx.x >> 6);
    int lane = threadIdx.x & 63;
    int t   = wave / (B * C);
    int rem = wave - t * (B * C);
    int b   = rem >> 8;
    int c   = rem & 255;
    const float* src = (t == 0) ? y : (t == 1) ? x0 : (t == 2) ? x1
                                    : (t == 3) ? x2 : x3;
    const float4* p = (const float4*)(src + (size_t)(b * C + c) * HW);
    float4 v0 = p[lane];
    float4 v1 = p[lane + 64];
    float4 v2 = p[lane + 128];
    float4 v3 = p[lane + 192];
    float s = v0.x + v0.y + v0.z + v0.w
            + v1.x + v1.y + v1.z + v1.w
            + v2.x + v2.y + v2.z + v2.w
            + v3.x + v3.y + v3.z + v3.w;
#pragma unroll
    for (int m = 32; m >= 1; m >>= 1) s += __shfl_xor(s, m);
    if (lane == 0) feats[b * FEAT + t * C + c] = s * (1.0f / 1024.0f);
}

// ---------------------------------------------------------------------------
// Kernel 2 (round-3): gate MLP, one 512-thread block per batch element.
// GEMM1 coalesced: wave w owns rows 4w..4w+3 of conv1_w.
// ---------------------------------------------------------------------------
__global__ __launch_bounds__(512) void gate_kernel(
    const float* __restrict__ feats,
    const float* __restrict__ conv1_w,   // [MID][FEAT]
    const float* __restrict__ bn_gamma, const float* __restrict__ bn_beta,
    const float* __restrict__ bn_mean,  const float* __restrict__ bn_var,
    const float* __restrict__ conv2_w,   // [FEAT][MID]
    const float* __restrict__ conv2_b,   // [FEAT]
    float* __restrict__ gates)           // [B][NT][C]
{
    __shared__ __align__(16) float feats_s[FEAT];
    __shared__ float h_s[MID];

    const int b    = blockIdx.x;
    const int tid  = threadIdx.x;
    const int wave = tid >> 6;
    const int lane = tid & 63;

    for (int i = tid; i < FEAT; i += 512) feats_s[i] = feats[b * FEAT + i];
    __syncthreads();

    const float4* fs = (const float4*)feats_s;
    float4 wv[4][5];
#pragma unroll
    for (int r = 0; r < 4; ++r) {
        const float4* wp = (const float4*)(conv1_w + (wave * 4 + r) * FEAT);
#pragma unroll
        for (int k = 0; k < 5; ++k) wv[r][k] = wp[lane + 64 * k];
    }
    float a0 = 0.f, a1 = 0.f, a2 = 0.f, a3 = 0.f;
#pragma unroll
    for (int k = 0; k < 5; ++k) {
        float4 f = fs[lane + 64 * k];
        a0 += wv[0][k].x * f.x + wv[0][k].y * f.y + wv[0][k].z * f.z + wv[0][k].w * f.w;
        a1 += wv[1][k].x * f.x + wv[1][k].y * f.y + wv[1][k].z * f.z + wv[1][k].w * f.w;
        a2 += wv[2][k].x * f.x + wv[2][k].y * f.y + wv[2][k].z * f.z + wv[2][k].w * f.w;
        a3 += wv[3][k].x * f.x + wv[3][k].y * f.y + wv[3][k].z * f.z + wv[3][k].w * f.w;
    }
#pragma unroll
    for (int m = 32; m >= 1; m >>= 1) {
        a0 += __shfl_xor(a0, m);
        a1 += __shfl_xor(a1, m);
        a2 += __shfl_xor(a2, m);
        a3 += __shfl_xor(a3, m);
    }
    if (lane == 0) {
        float acc[4] = {a0, a1, a2, a3};
#pragma unroll
        for (int r = 0; r < 4; ++r) {
            const int m = wave * 4 + r;
            float inv = rsqrtf(bn_var[m] + EPS);
            float hv  = (acc[r] - bn_mean[m]) * (bn_gamma[m] * inv) + bn_beta[m];
            h_s[m] = fmaxf(hv, 0.f);
        }
    }
    __syncthreads();

    if (tid < 256) {
        float wvout[5];
#pragma unroll
        for (int r = 0; r < 5; ++r) {
            const int j = r * 256 + tid;
            const float4* w2 = (const float4*)(conv2_w + j * MID);
            float a = conv2_b[j];
#pragma unroll
            for (int i = 0; i < 8; ++i) {
                float4 q = w2[i];
                a += q.x * h_s[i * 4]     + q.y * h_s[i * 4 + 1]
                   + q.z * h_s[i * 4 + 2] + q.w * h_s[i * 4 + 3];
            }
            wvout[r] = a;
        }
        const float w1 = 1.f / (1.f + expf(-wvout[0]));
        const float mx = fmaxf(fmaxf(wvout[1], wvout[2]), fmaxf(wvout[3], wvout[4]));
        const float e1 = expf(wvout[1] - mx), e2 = expf(wvout[2] - mx);
        const float e3 = expf(wvout[3] - mx), e4 = expf(wvout[4] - mx);
        const float inv = 1.f / (e1 + e2 + e3 + e4);
        gates[b * FEAT +        tid] = w1;
        gates[b * FEAT +  256 + tid] = e1 * inv;
        gates[b * FEAT +  512 + tid] = e2 * inv;
        gates[b * FEAT +  768 + tid] = e3 * inv;
        gates[b * FEAT + 1024 + tid] = e4 * inv;
    }
}

// ---------------------------------------------------------------------------
// Kernel 3: flat grid-stride gated sum (copy-bench shape: 2048 blocks x 256).
// out = g0*y + g1*x0 + g2*x1 + g3*x2 + g4*x3.  Plain stores — NT stores to
// d_out broke post-timing validation (stale cached poison lines, round 7).
// ---------------------------------------------------------------------------
__global__ __launch_bounds__(K3_THR) void out_kernel(
    const float* __restrict__ y,
    const float* __restrict__ x0, const float* __restrict__ x1,
    const float* __restrict__ x2, const float* __restrict__ x3,
    const float* __restrict__ gates,
    float* __restrict__ out)
{
    const int gtid = blockIdx.x * K3_THR + threadIdx.x;
    const float4* py = (const float4*)y;
    const float4* p0 = (const float4*)x0;
    const float4* p1 = (const float4*)x1;
    const float4* p2 = (const float4*)x2;
    const float4* p3 = (const float4*)x3;
    float4* po = (float4*)out;
#pragma unroll 2
    for (int f = gtid; f < OUT_F4; f += K3_TOT) {
        const int slice = f >> 8;            // 256 float4 per (b,c) slice
        const int b = slice >> 8;
        const int c = slice & 255;
        const float* gb = gates + b * FEAT + c;
        const float g0 = gb[0],   g1 = gb[256], g2 = gb[512];
        const float g3 = gb[768], g4 = gb[1024];
        float4 vy = py[f], v0 = p0[f], v1 = p1[f], v2 = p2[f], v3 = p3[f];
        float4 r;
        r.x = vy.x * g0 + v0.x * g1 + v1.x * g2 + v2.x * g3 + v3.x * g4;
        r.y = vy.y * g0 + v0.y * g1 + v1.y * g2 + v2.y * g3 + v3.y * g4;
        r.z = vy.z * g0 + v0.z * g1 + v1.z * g2 + v2.z * g3 + v3.z * g4;
        r.w = vy.w * g0 + v0.w * g1 + v1.w * g2 + v2.w * g3 + v3.w * g4;
        po[f] = r;
    }
}

// ---------------------------------------------------------------------------
extern "C" void kernel_launch(void* const* d_in, const int* in_sizes, int n_in,
                              void* d_out, int out_size, void* d_ws, size_t ws_size,
                              hipStream_t stream) {
    const float* y        = (const float*)d_in[0];
    const float* x0       = (const float*)d_in[1];
    const float* x1       = (const float*)d_in[2];
    const float* x2       = (const float*)d_in[3];
    const float* x3       = (const float*)d_in[4];
    const float* conv1_w  = (const float*)d_in[5];
    const float* bn_gamma = (const float*)d_in[6];
    const float* bn_beta  = (const float*)d_in[7];
    const float* bn_mean  = (const float*)d_in[8];
    const float* bn_var   = (const float*)d_in[9];
    const float* conv2_w  = (const float*)d_in[10];
    const float* conv2_b  = (const float*)d_in[11];

    float* feats = (float*)d_ws;             // [B][FEAT]
    float* gates = feats + B * FEAT;         // [B][NT][C]
    float* out   = (float*)d_out;

    mean_kernel<<<(NT * B * C) / 4, 256, 0, stream>>>(y, x0, x1, x2, x3, feats);
    gate_kernel<<<B, 512, 0, stream>>>(feats, conv1_w, bn_gamma, bn_beta,
                                       bn_mean, bn_var, conv2_w, conv2_b, gates);
    out_kernel<<<K3_BLKS, K3_THR, 0, stream>>>(y, x0, x1, x2, x3, gates, out);
}